// Round 6
// baseline (72.899 us; speedup 1.0000x reference)
//
#include <hip/hip_runtime.h>

#define NN 8192
#define DD 128
#define BR 128          // anchors per block
#define BC 64           // cols per LDS tile
#define NC 16           // column chunks (grid.y)
#define NCLS 100
#define CAPR 192        // max rows per class

typedef short bf16x8v __attribute__((ext_vector_type(8)));
typedef float f32x4  __attribute__((ext_vector_type(4)));

constexpr float SSCALE  = 3.7982825265208916f; // sqrt((1/T)*log2(e))
constexpr float LN2     = 0.6931471805599453f;
constexpr float NEG_BIG = -1.0e30f;
constexpr float M_INIT  = -3.0e38f;

__device__ __forceinline__ float ex2(float x) { return __builtin_amdgcn_exp2f(x); }

// ---------------- kernel 1: fp32 -> bf16 (RNE), pre-scaled by sqrt(SCALE2) ----------------
__global__ __launch_bounds__(256) void k_convert(const float* __restrict__ z,
                                                 unsigned short* __restrict__ zb) {
  int i = blockIdx.x * blockDim.x + threadIdx.x;
  const float4 v = reinterpret_cast<const float4*>(z)[i];
  auto cvt = [](float f) -> unsigned short {
    unsigned u = __float_as_uint(f);
    unsigned r = (u + 0x7fffu + ((u >> 16) & 1u)) >> 16;
    return (unsigned short)r;
  };
  ushort4 o;
  o.x = cvt(v.x * SSCALE); o.y = cvt(v.y * SSCALE);
  o.z = cvt(v.z * SSCALE); o.w = cvt(v.w * SSCALE);
  reinterpret_cast<ushort4*>(zb)[i] = o;
}

// ---- async global->LDS staging of one 64x128 bf16 tile (16KB) ----
__device__ __forceinline__ void stage_tile(const unsigned short* __restrict__ zb,
                                           int gc0, unsigned short* __restrict__ bufc,
                                           int tid) {
#pragma unroll
  for (int q = 0; q < 4; ++q) {
    int c = q * 256 + tid;          // 16B chunk index, 1024 total
    int r = c >> 4;                 // row within tile (0..63)
    int w = c & 15;                 // 16B slot within row
    int wsrc = w ^ (r & 7);         // inverse swizzle (XOR involution)
    const unsigned short* g = zb + ((size_t)(gc0 + r) << 7) + (wsrc << 3);
    __builtin_amdgcn_global_load_lds(
        (const __attribute__((address_space(1))) void*)(uintptr_t)g,
        (__attribute__((address_space(3))) void*)(unsigned)(uintptr_t)(bufc + (c << 3)),
        16, 0, 0);
  }
}

// ---------------- per-tile pure LSE epilogue (label-free) ----------------
// acc[t][st][r]: local col = dcl + st*16 + lg*4 + r (rel. to wave's anchor frame
// when HD), local row (anchor) = t*16 + lr.
template<bool HD>
__device__ __forceinline__ void tile_lse(const f32x4 (&acc)[4][2], int dcl,
                                         int lr, int lg, float (&m)[4], float (&s)[4]) {
#pragma unroll
  for (int t = 0; t < 4; ++t) {
    float x[8];
#pragma unroll
    for (int st = 0; st < 2; ++st) {
#pragma unroll
      for (int r = 0; r < 4; ++r) {
        float v = acc[t][st][r];
        if (HD) {
          bool dg = (dcl + st * 16 + lg * 4 + r) == (t * 16 + lr);
          v = dg ? NEG_BIG : v;
        }
        x[st * 4 + r] = v;
      }
    }
    float m4a = fmaxf(x[0], x[4]), m4b = fmaxf(x[1], x[5]);
    float m4c = fmaxf(x[2], x[6]), m4d = fmaxf(x[3], x[7]);
    float tm = fmaxf(fmaxf(m4a, m4b), fmaxf(m4c, m4d));
    float mn = fmaxf(m[t], tm);
    float e0 = ex2(x[0] - mn) + ex2(x[4] - mn);
    float e1 = ex2(x[1] - mn) + ex2(x[5] - mn);
    float e2 = ex2(x[2] - mn) + ex2(x[6] - mn);
    float e3 = ex2(x[3] - mn) + ex2(x[7] - mn);
    s[t] = fmaf(s[t], ex2(m[t] - mn), (e0 + e1) + (e2 + e3));
    m[t] = mn;
  }
}

// ---------------- kernel 2: Gram + online LSE ----------------
// 4 waves = 2 anchor-halves (wa) x 2 col-halves (wc).
// Wave: 64 anchors (bfr[4][4], hoisted) x 32 of the tile's 64 cols.
__global__ __launch_bounds__(256) void k_main(const unsigned short* __restrict__ zb,
                                              float2* __restrict__ partials,
                                              int cpc, int nt) {
  __shared__ unsigned short lds_a[2][BC * DD];   // 2 x 16KB

  const int tid  = threadIdx.x;
  const int lane = tid & 63;
  const int w    = tid >> 6;
  const int wa = w >> 1, wc = w & 1;
  const int lr = lane & 15, lg = lane >> 4;
  const int rx = lr & 7;
  const int rowbase  = blockIdx.x * BR;
  const int rowstart = rowbase + wa * 64;        // wave's first anchor
  const int cb       = blockIdx.y;
  const int cStart   = cb * cpc;

  // hoisted anchor (B) fragments: 4 t-subtiles x 4 K-steps = 64 VGPR
  bf16x8v bfr[4][4];
#pragma unroll
  for (int t = 0; t < 4; ++t) {
    int row = rowstart + t * 16 + lr;
#pragma unroll
    for (int ks = 0; ks < 4; ++ks)
      bfr[t][ks] = *reinterpret_cast<const bf16x8v*>(zb + (size_t)row * DD + ks * 32 + lg * 8);
  }

  stage_tile(zb, cStart, lds_a[0], tid);

  int woff[4];
#pragma unroll
  for (int ks = 0; ks < 4; ++ks) woff[ks] = ((ks * 4 + lg) ^ rx) << 3;

  float m[4], s[4];
#pragma unroll
  for (int t = 0; t < 4; ++t) { m[t] = M_INIT; s[t] = 0.f; }
  __syncthreads();

  int cur = 0;
  for (int tt = 0; tt < nt; ++tt) {
    const int c0 = cStart + tt * BC;
    if (tt + 1 < nt) stage_tile(zb, c0 + BC, lds_a[cur ^ 1], tid);

    const unsigned short* bufc = lds_a[cur];
    // load all A fragments up-front (8 x ds_read_b128, 32 VGPR)
    bf16x8v afr[2][4];
#pragma unroll
    for (int st = 0; st < 2; ++st) {
      const unsigned short* rp = bufc + (wc * 32 + st * 16 + lr) * DD;
#pragma unroll
      for (int ks = 0; ks < 4; ++ks)
        afr[st][ks] = *reinterpret_cast<const bf16x8v*>(rp + woff[ks]);
    }

    f32x4 acc[4][2];
#pragma unroll
    for (int t = 0; t < 4; ++t) {
#pragma unroll
      for (int st = 0; st < 2; ++st) {
        f32x4 a = (f32x4){0.f, 0.f, 0.f, 0.f};
        a = __builtin_amdgcn_mfma_f32_16x16x32_bf16(afr[st][0], bfr[t][0], a, 0, 0, 0);
        a = __builtin_amdgcn_mfma_f32_16x16x32_bf16(afr[st][1], bfr[t][1], a, 0, 0, 0);
        a = __builtin_amdgcn_mfma_f32_16x16x32_bf16(afr[st][2], bfr[t][2], a, 0, 0, 0);
        a = __builtin_amdgcn_mfma_f32_16x16x32_bf16(afr[st][3], bfr[t][3], a, 0, 0, 0);
        acc[t][st] = a;
      }
    }

    // wave's 32-col territory intersects its 64-anchor diagonal iff dcl in {0,32}
    const int dcl = c0 + wc * 32 - rowstart;
    if (dcl == 0 || dcl == 32) tile_lse<true >(acc, dcl, lr, lg, m, s);
    else                       tile_lse<false>(acc, 0,   lr, lg, m, s);

    __syncthreads();
    cur ^= 1;
  }

  // merge the 4 lane-groups (xor 16, 32)
#pragma unroll
  for (int off = 16; off <= 32; off <<= 1) {
#pragma unroll
    for (int t = 0; t < 4; ++t) {
      float mo = __shfl_xor(m[t], off);
      float so = __shfl_xor(s[t], off);
      float mn = fmaxf(m[t], mo);
      s[t] = s[t] * ex2(m[t] - mn) + so * ex2(mo - mn);
      m[t] = mn;
    }
  }
  if (lg == 0) {
    const int ch = cb * 2 + wc;                  // 32 chunks per row
#pragma unroll
    for (int t = 0; t < 4; ++t)
      partials[(size_t)ch * NN + rowstart + t * 16 + lr] = make_float2(m[t], s[t]);
  }
}

// ---------------- kernel 3: per-class exact correction + per-class loss ----------------
__global__ __launch_bounds__(256) void k_corr(const unsigned short* __restrict__ zb,
                                              const int* __restrict__ labels,
                                              const float2* __restrict__ partials,
                                              float* __restrict__ clsum, int nch) {
  const int c = blockIdx.x;
  const int tid = threadIdx.x, lane = tid & 63, w = tid >> 6;
  __shared__ int rows[CAPR];
  __shared__ float rowm[CAPR], rowss[CAPR];
  __shared__ int nsh;
  __shared__ float clpart[4];

  // wave-synchronous deterministic compaction (wave 0 only)
  if (w == 0) {
    int base = 0;
    for (int rd = 0; rd < NN / 256; ++rd) {
      int4 v = *reinterpret_cast<const int4*>(labels + rd * 256 + lane * 4);
      int labq[4] = {v.x, v.y, v.z, v.w};
#pragma unroll
      for (int q = 0; q < 4; ++q) {
        bool mt = (labq[q] == c);
        unsigned long long mask = __ballot(mt);
        if (mt) {
          int p = base + __popcll(mask & ((1ull << lane) - 1ull));
          if (p < CAPR) rows[p] = rd * 256 + lane * 4 + q;
        }
        base += __popcll(mask);
      }
    }
    if (lane == 0) nsh = base < CAPR ? base : CAPR;
  }
  __syncthreads();
  const int n = nsh;
  if (n < 2) { if (tid == 0) clsum[c] = 0.f; return; }

  // merge the nch chunk-partials per row
  for (int r = tid; r < n; r += 256) {
    int row = rows[r];
    float m = M_INIT, s = 0.f;
    for (int ch = 0; ch < nch; ++ch) {
      float2 p = partials[(size_t)ch * NN + row];
      float mn = fmaxf(m, p.x);
      s = s * ex2(m - mn) + p.y * ex2(p.x - mn);
      m = mn;
    }
    rowm[r] = m; rowss[r] = s;
  }
  __syncthreads();

  const int lr = lane & 15, lg = lane >> 4;
  const int NB = (n + 15) >> 4;
  float wloss = 0.f;
  for (int ab = w; ab < NB; ab += 4) {
    int a = ab * 16 + lr;
    bool aok = a < n;
    int ga = rows[aok ? a : 0];
    bf16x8v bf[4];
#pragma unroll
    for (int ks = 0; ks < 4; ++ks)
      bf[ks] = *reinterpret_cast<const bf16x8v*>(zb + (size_t)ga * DD + ks * 32 + lg * 8);
    float ma = aok ? rowm[a] : 0.f;
    float sumv = 0.f, sume = 0.f;
    for (int bb = 0; bb < NB; ++bb) {
      int bi = bb * 16 + lr;
      int gb = rows[bi < n ? bi : 0];
      bf16x8v af[4];
#pragma unroll
      for (int ks = 0; ks < 4; ++ks)
        af[ks] = *reinterpret_cast<const bf16x8v*>(zb + (size_t)gb * DD + ks * 32 + lg * 8);
      f32x4 acc = (f32x4){0.f, 0.f, 0.f, 0.f};
      acc = __builtin_amdgcn_mfma_f32_16x16x32_bf16(af[0], bf[0], acc, 0, 0, 0);
      acc = __builtin_amdgcn_mfma_f32_16x16x32_bf16(af[1], bf[1], acc, 0, 0, 0);
      acc = __builtin_amdgcn_mfma_f32_16x16x32_bf16(af[2], bf[2], acc, 0, 0, 0);
      acc = __builtin_amdgcn_mfma_f32_16x16x32_bf16(af[3], bf[3], acc, 0, 0, 0);
#pragma unroll
      for (int r = 0; r < 4; ++r) {
        int b = bb * 16 + lg * 4 + r;
        bool ok = (b < n) && (b != a);
        float v = acc[r];
        sumv += ok ? v : 0.f;
        float e = ex2(v - ma);
        sume += ok ? e : 0.f;
      }
    }
#pragma unroll
    for (int off = 16; off <= 32; off <<= 1) {
      sumv += __shfl_xor(sumv, off);
      sume += __shfl_xor(sume, off);
    }
    if (lg == 0 && aok) {
      float sp = rowss[a] - 0.5f * sume;            // apply 0.5 weight to matches
      wloss += LN2 * (ma + log2f(sp)) - LN2 * sumv / (float)(n - 1);
    }
  }
#pragma unroll
  for (int off = 32; off >= 1; off >>= 1) wloss += __shfl_xor(wloss, off);
  if (lane == 0) clpart[w] = wloss;
  __syncthreads();
  if (tid == 0) clsum[c] = (clpart[0] + clpart[1]) + (clpart[2] + clpart[3]);
}

// ---------------- kernel 4: final sum over classes ----------------
__global__ __launch_bounds__(128) void k_final(const float* __restrict__ clsum,
                                               float* __restrict__ out) {
  const int tid = threadIdx.x;
  float v = (tid < NCLS) ? clsum[tid] : 0.f;
#pragma unroll
  for (int off = 32; off >= 1; off >>= 1) v += __shfl_xor(v, off);
  __shared__ float t2[2];
  if ((tid & 63) == 0) t2[tid >> 6] = v;
  __syncthreads();
  if (tid == 0) out[0] = (t2[0] + t2[1]) * (1.0f / (float)NN);
}

extern "C" void kernel_launch(void* const* d_in, const int* in_sizes, int n_in,
                              void* d_out, int out_size, void* d_ws, size_t ws_size,
                              hipStream_t stream) {
  const float* z      = (const float*)d_in[0];
  const int*   labels = (const int*)d_in[1];

  const int cpc = NN / NC;       // 512
  const int nt  = cpc / BC;      // 8
  const int nch = NC * 2;        // 32 partial chunks per row

  char* ws = (char*)d_ws;
  unsigned short* zb = (unsigned short*)ws;                                  // 2 MB
  float2* partials   = (float2*)(ws + (size_t)NN * DD * 2);                  // nch*NN*8 = 2 MB
  float*  clsum      = (float*)(ws + (size_t)NN * DD * 2 + (size_t)nch * NN * 8);

  hipLaunchKernelGGL(k_convert, dim3(NN * DD / 4 / 256), dim3(256), 0, stream, z, zb);
  hipLaunchKernelGGL(k_main,    dim3(NN / BR, NC), dim3(256), 0, stream, zb, partials, cpc, nt);
  hipLaunchKernelGGL(k_corr,    dim3(NCLS), dim3(256), 0, stream, zb, labels, partials, clsum, nch);
  hipLaunchKernelGGL(k_final,   dim3(1), dim3(128), 0, stream, clsum, (float*)d_out);
}

// Round 7
// 68.601 us; speedup vs baseline: 1.0626x; 1.0626x over previous
//
#include <hip/hip_runtime.h>

#define NN 8192
#define DD 128
#define NC 32           // column chunks (grid.y)
#define CPC (NN / NC)   // 256 cols per chunk
#define AW 64           // anchors per wave
#define NCLS 100
#define CAPR 192        // max rows per class

typedef short bf16x8v __attribute__((ext_vector_type(8)));
typedef float f32x4  __attribute__((ext_vector_type(4)));

constexpr float SSCALE  = 3.7982825265208916f; // sqrt((1/T)*log2(e))
constexpr float LN2     = 0.6931471805599453f;
constexpr float NEG_BIG = -1.0e30f;
constexpr float M_INIT  = -3.0e38f;

__device__ __forceinline__ float ex2(float x) { return __builtin_amdgcn_exp2f(x); }

// ---------------- kernel 1: fp32 -> bf16 (RNE), pre-scaled by sqrt(SCALE2) ----------------
__global__ __launch_bounds__(256) void k_convert(const float* __restrict__ z,
                                                 unsigned short* __restrict__ zb) {
  int i = blockIdx.x * blockDim.x + threadIdx.x;
  const float4 v = reinterpret_cast<const float4*>(z)[i];
  auto cvt = [](float f) -> unsigned short {
    unsigned u = __float_as_uint(f);
    unsigned r = (u + 0x7fffu + ((u >> 16) & 1u)) >> 16;
    return (unsigned short)r;
  };
  ushort4 o;
  o.x = cvt(v.x * SSCALE); o.y = cvt(v.y * SSCALE);
  o.z = cvt(v.z * SSCALE); o.w = cvt(v.w * SSCALE);
  reinterpret_cast<ushort4*>(zb)[i] = o;
}

// ---------------- per-16-col-tile pure LSE (label-free) ----------------
template<bool HD>
__device__ __forceinline__ void tile_lse(const f32x4 (&acc)[4], int dcl,
                                         int lr, int lg, float (&m)[4], float (&s)[4]) {
  const int jl = lg * 4;
#pragma unroll
  for (int t = 0; t < 4; ++t) {
    float x0 = acc[t][0], x1 = acc[t][1], x2 = acc[t][2], x3 = acc[t][3];
    if (HD) {
      int al = t * 16 + lr - dcl;        // diagonal iff al == jl + r
      x0 = (al == jl + 0) ? NEG_BIG : x0;
      x1 = (al == jl + 1) ? NEG_BIG : x1;
      x2 = (al == jl + 2) ? NEG_BIG : x2;
      x3 = (al == jl + 3) ? NEG_BIG : x3;
    }
    float tm = fmaxf(fmaxf(x0, x1), fmaxf(x2, x3));
    float mn = fmaxf(m[t], tm);
    float e = (ex2(x0 - mn) + ex2(x1 - mn)) + (ex2(x2 - mn) + ex2(x3 - mn));
    s[t] = fmaf(s[t], ex2(m[t] - mn), e);
    m[t] = mn;
  }
}

// ---------------- kernel 2: Gram + online LSE — no LDS, no barriers ----------------
// Each wave is fully independent: 64 anchors (bfr hoisted) x 256-col chunk,
// A fragments streamed straight from L2-resident zb in 16-col tiles.
__global__ __launch_bounds__(256) void k_main(const unsigned short* __restrict__ zb,
                                              float2* __restrict__ partials) {
  const int tid  = threadIdx.x;
  const int lane = tid & 63;
  const int w    = tid >> 6;
  const int lr = lane & 15, lg = lane >> 4;
  const int rowstart = (blockIdx.x * 4 + w) * AW;  // wave's first anchor
  const int cb       = blockIdx.y;
  const int cStart   = cb * CPC;

  // hoisted anchor (B) fragments: 4 t-subtiles x 4 K-steps = 64 VGPR
  bf16x8v bfr[4][4];
#pragma unroll
  for (int t = 0; t < 4; ++t) {
    const unsigned short* rp = zb + (size_t)(rowstart + t * 16 + lr) * DD + lg * 8;
#pragma unroll
    for (int ks = 0; ks < 4; ++ks)
      bfr[t][ks] = *reinterpret_cast<const bf16x8v*>(rp + ks * 32);
  }

  float m[4], s[4];
#pragma unroll
  for (int t = 0; t < 4; ++t) { m[t] = M_INIT; s[t] = 0.f; }

  for (int tt = 0; tt < CPC / 16; ++tt) {
    const int c0 = cStart + tt * 16;
    // A fragments for 16 j-rows, straight from global (L2 hit)
    const unsigned short* rp = zb + (size_t)(c0 + lr) * DD + lg * 8;
    bf16x8v a0 = *reinterpret_cast<const bf16x8v*>(rp);
    bf16x8v a1 = *reinterpret_cast<const bf16x8v*>(rp + 32);
    bf16x8v a2 = *reinterpret_cast<const bf16x8v*>(rp + 64);
    bf16x8v a3 = *reinterpret_cast<const bf16x8v*>(rp + 96);

    f32x4 acc[4];
#pragma unroll
    for (int t = 0; t < 4; ++t) {
      f32x4 a = (f32x4){0.f, 0.f, 0.f, 0.f};
      a = __builtin_amdgcn_mfma_f32_16x16x32_bf16(a0, bfr[t][0], a, 0, 0, 0);
      a = __builtin_amdgcn_mfma_f32_16x16x32_bf16(a1, bfr[t][1], a, 0, 0, 0);
      a = __builtin_amdgcn_mfma_f32_16x16x32_bf16(a2, bfr[t][2], a, 0, 0, 0);
      a = __builtin_amdgcn_mfma_f32_16x16x32_bf16(a3, bfr[t][3], a, 0, 0, 0);
      acc[t] = a;
    }

    const int dcl = c0 - rowstart;
    if ((unsigned)dcl < (unsigned)AW) tile_lse<true >(acc, dcl, lr, lg, m, s);
    else                              tile_lse<false>(acc, 0,   lr, lg, m, s);
  }

  // merge the 4 lane-groups (xor 16, 32)
#pragma unroll
  for (int off = 16; off <= 32; off <<= 1) {
#pragma unroll
    for (int t = 0; t < 4; ++t) {
      float mo = __shfl_xor(m[t], off);
      float so = __shfl_xor(s[t], off);
      float mn = fmaxf(m[t], mo);
      s[t] = s[t] * ex2(m[t] - mn) + so * ex2(mo - mn);
      m[t] = mn;
    }
  }
  if (lg == 0) {
#pragma unroll
    for (int t = 0; t < 4; ++t)
      partials[(size_t)(rowstart + t * 16 + lr) * NC + cb] = make_float2(m[t], s[t]);
  }
}

// ---------------- kernel 3: merge the NC chunk-partials per row (coalesced) ----------------
__global__ __launch_bounds__(256) void k_merge(const float2* __restrict__ partials,
                                               float2* __restrict__ rowms) {
  const int gid = blockIdx.x * 256 + threadIdx.x;
  const int row = gid >> 2, part = gid & 3;
  const float2* p = partials + (size_t)row * NC + part * (NC / 4);
  float m = M_INIT, s = 0.f;
#pragma unroll
  for (int k = 0; k < NC / 4; ++k) {
    float2 q = p[k];
    float mn = fmaxf(m, q.x);
    s = s * ex2(m - mn) + q.y * ex2(q.x - mn);
    m = mn;
  }
#pragma unroll
  for (int off = 1; off <= 2; off <<= 1) {
    float mo = __shfl_xor(m, off);
    float so = __shfl_xor(s, off);
    float mn = fmaxf(m, mo);
    s = s * ex2(m - mn) + so * ex2(mo - mn);
    m = mn;
  }
  if (part == 0) rowms[row] = make_float2(m, s);
}

// ---------------- kernel 4: per-class exact correction + per-class loss ----------------
__global__ __launch_bounds__(256) void k_corr(const unsigned short* __restrict__ zb,
                                              const int* __restrict__ labels,
                                              const float2* __restrict__ rowms,
                                              float* __restrict__ clsum) {
  const int c = blockIdx.x;
  const int tid = threadIdx.x, lane = tid & 63, w = tid >> 6;
  __shared__ int rows[CAPR];
  __shared__ int nsh;
  __shared__ float clpart[4];

  // wave-synchronous deterministic compaction (wave 0 only)
  if (w == 0) {
    int base = 0;
    for (int rd = 0; rd < NN / 256; ++rd) {
      int4 v = *reinterpret_cast<const int4*>(labels + rd * 256 + lane * 4);
      int labq[4] = {v.x, v.y, v.z, v.w};
#pragma unroll
      for (int q = 0; q < 4; ++q) {
        bool mt = (labq[q] == c);
        unsigned long long mask = __ballot(mt);
        if (mt) {
          int p = base + __popcll(mask & ((1ull << lane) - 1ull));
          if (p < CAPR) rows[p] = rd * 256 + lane * 4 + q;
        }
        base += __popcll(mask);
      }
    }
    if (lane == 0) nsh = base < CAPR ? base : CAPR;
  }
  __syncthreads();
  const int n = nsh;
  if (n < 2) { if (tid == 0) clsum[c] = 0.f; return; }

  const int lr = lane & 15, lg = lane >> 4;
  const int NB = (n + 15) >> 4;
  float wloss = 0.f;
  for (int ab = w; ab < NB; ab += 4) {
    int a = ab * 16 + lr;
    bool aok = a < n;
    int ga = rows[aok ? a : 0];
    bf16x8v bf[4];
#pragma unroll
    for (int ks = 0; ks < 4; ++ks)
      bf[ks] = *reinterpret_cast<const bf16x8v*>(zb + (size_t)ga * DD + ks * 32 + lg * 8);
    float2 pm = rowms[ga];
    float ma = pm.x;
    float sumv = 0.f, sume = 0.f;
    for (int bb = 0; bb < NB; ++bb) {
      int bi = bb * 16 + lr;
      int gb = rows[bi < n ? bi : 0];
      bf16x8v af[4];
#pragma unroll
      for (int ks = 0; ks < 4; ++ks)
        af[ks] = *reinterpret_cast<const bf16x8v*>(zb + (size_t)gb * DD + ks * 32 + lg * 8);
      f32x4 acc = (f32x4){0.f, 0.f, 0.f, 0.f};
      acc = __builtin_amdgcn_mfma_f32_16x16x32_bf16(af[0], bf[0], acc, 0, 0, 0);
      acc = __builtin_amdgcn_mfma_f32_16x16x32_bf16(af[1], bf[1], acc, 0, 0, 0);
      acc = __builtin_amdgcn_mfma_f32_16x16x32_bf16(af[2], bf[2], acc, 0, 0, 0);
      acc = __builtin_amdgcn_mfma_f32_16x16x32_bf16(af[3], bf[3], acc, 0, 0, 0);
#pragma unroll
      for (int r = 0; r < 4; ++r) {
        int b = bb * 16 + lg * 4 + r;
        bool ok = (b < n) && (b != a);
        float v = acc[r];
        sumv += ok ? v : 0.f;
        float e = ex2(v - ma);
        sume += ok ? e : 0.f;
      }
    }
#pragma unroll
    for (int off = 16; off <= 32; off <<= 1) {
      sumv += __shfl_xor(sumv, off);
      sume += __shfl_xor(sume, off);
    }
    if (lg == 0 && aok) {
      float sp = pm.y - 0.5f * sume;               // apply 0.5 weight to matches
      wloss += LN2 * (ma + log2f(sp)) - LN2 * sumv / (float)(n - 1);
    }
  }
#pragma unroll
  for (int off = 32; off >= 1; off >>= 1) wloss += __shfl_xor(wloss, off);
  if (lane == 0) clpart[w] = wloss;
  __syncthreads();
  if (tid == 0) clsum[c] = (clpart[0] + clpart[1]) + (clpart[2] + clpart[3]);
}

// ---------------- kernel 5: final sum over classes ----------------
__global__ __launch_bounds__(128) void k_final(const float* __restrict__ clsum,
                                               float* __restrict__ out) {
  const int tid = threadIdx.x;
  float v = (tid < NCLS) ? clsum[tid] : 0.f;
#pragma unroll
  for (int off = 32; off >= 1; off >>= 1) v += __shfl_xor(v, off);
  __shared__ float t2[2];
  if ((tid & 63) == 0) t2[tid >> 6] = v;
  __syncthreads();
  if (tid == 0) out[0] = (t2[0] + t2[1]) * (1.0f / (float)NN);
}

extern "C" void kernel_launch(void* const* d_in, const int* in_sizes, int n_in,
                              void* d_out, int out_size, void* d_ws, size_t ws_size,
                              hipStream_t stream) {
  const float* z      = (const float*)d_in[0];
  const int*   labels = (const int*)d_in[1];

  char* ws = (char*)d_ws;
  unsigned short* zb = (unsigned short*)ws;                                   // 2 MB
  float2* partials   = (float2*)(ws + (size_t)NN * DD * 2);                   // NN*NC*8 = 2 MB
  float2* rowms      = (float2*)(ws + (size_t)NN * DD * 2 + (size_t)NN * NC * 8);   // 64 KB
  float*  clsum      = (float*)(ws + (size_t)NN * DD * 2 + (size_t)NN * NC * 8 + (size_t)NN * 8);

  hipLaunchKernelGGL(k_convert, dim3(NN * DD / 4 / 256), dim3(256), 0, stream, z, zb);
  hipLaunchKernelGGL(k_main,    dim3(NN / (4 * AW), NC), dim3(256), 0, stream, zb, partials);
  hipLaunchKernelGGL(k_merge,   dim3(NN * 4 / 256), dim3(256), 0, stream, partials, rowms);
  hipLaunchKernelGGL(k_corr,    dim3(NCLS), dim3(256), 0, stream, zb, labels, rowms, clsum);
  hipLaunchKernelGGL(k_final,   dim3(1), dim3(128), 0, stream, clsum, (float*)d_out);
}

// Round 8
// 66.697 us; speedup vs baseline: 1.0930x; 1.0286x over previous
//
#include <hip/hip_runtime.h>

#define NN 8192
#define DD 128
#define NC 32           // column chunks (grid.y)
#define CPC (NN / NC)   // 256 cols per chunk
#define AW 64           // anchors per wave
#define NCLS 100
#define CAPR 192        // max rows per class

typedef short bf16x8v __attribute__((ext_vector_type(8)));
typedef float f32x4  __attribute__((ext_vector_type(4)));

constexpr float SSCALE  = 3.7982825265208916f; // sqrt((1/T)*log2(e))
constexpr float LN2     = 0.6931471805599453f;
constexpr float NEG_BIG = -1.0e30f;
constexpr float M_INIT  = -3.0e38f;

__device__ __forceinline__ float ex2(float x) { return __builtin_amdgcn_exp2f(x); }

// ---------------- kernel 1: fp32 -> bf16 (RNE), pre-scaled by sqrt(SCALE2) ----------------
__global__ __launch_bounds__(256) void k_convert(const float* __restrict__ z,
                                                 unsigned short* __restrict__ zb) {
  int i = blockIdx.x * blockDim.x + threadIdx.x;
  const float4 v = reinterpret_cast<const float4*>(z)[i];
  auto cvt = [](float f) -> unsigned short {
    unsigned u = __float_as_uint(f);
    unsigned r = (u + 0x7fffu + ((u >> 16) & 1u)) >> 16;
    return (unsigned short)r;
  };
  ushort4 o;
  o.x = cvt(v.x * SSCALE); o.y = cvt(v.y * SSCALE);
  o.z = cvt(v.z * SSCALE); o.w = cvt(v.w * SSCALE);
  reinterpret_cast<ushort4*>(zb)[i] = o;
}

// ---------------- per-16-col-tile pure LSE (label-free) ----------------
template<bool HD>
__device__ __forceinline__ void tile_lse(const f32x4 (&acc)[4], int dcl,
                                         int lr, int lg, float (&m)[4], float (&s)[4]) {
  const int jl = lg * 4;
#pragma unroll
  for (int t = 0; t < 4; ++t) {
    float x0 = acc[t][0], x1 = acc[t][1], x2 = acc[t][2], x3 = acc[t][3];
    if (HD) {
      int al = t * 16 + lr - dcl;        // diagonal iff al == jl + r
      x0 = (al == jl + 0) ? NEG_BIG : x0;
      x1 = (al == jl + 1) ? NEG_BIG : x1;
      x2 = (al == jl + 2) ? NEG_BIG : x2;
      x3 = (al == jl + 3) ? NEG_BIG : x3;
    }
    float tm = fmaxf(fmaxf(x0, x1), fmaxf(x2, x3));
    float mn = fmaxf(m[t], tm);
    float e = (ex2(x0 - mn) + ex2(x1 - mn)) + (ex2(x2 - mn) + ex2(x3 - mn));
    s[t] = fmaf(s[t], ex2(m[t] - mn), e);
    m[t] = mn;
  }
}

// ---------------- kernel 2: Gram + online LSE — no LDS, no barriers ----------------
// Wave: 64 anchors (bfr hoisted, 64 VGPR) x 256-col chunk; A-tiles streamed from
// L2-resident zb with a depth-1 register prefetch pipeline.
__global__ __launch_bounds__(256, 2) void k_main(const unsigned short* __restrict__ zb,
                                                 float2* __restrict__ partials) {
  const int tid  = threadIdx.x;
  const int lane = tid & 63;
  const int w    = tid >> 6;
  const int lr = lane & 15, lg = lane >> 4;
  const int rowstart = (blockIdx.x * 4 + w) * AW;  // wave's first anchor
  const int cb       = blockIdx.y;
  const int cStart   = cb * CPC;

  // hoisted anchor (B) fragments: 4 t-subtiles x 4 K-steps = 64 VGPR
  bf16x8v bfr[4][4];
#pragma unroll
  for (int t = 0; t < 4; ++t) {
    const unsigned short* rp = zb + (size_t)(rowstart + t * 16 + lr) * DD + lg * 8;
#pragma unroll
    for (int ks = 0; ks < 4; ++ks)
      bfr[t][ks] = *reinterpret_cast<const bf16x8v*>(rp + ks * 32);
  }

  float m[4], s[4];
#pragma unroll
  for (int t = 0; t < 4; ++t) { m[t] = M_INIT; s[t] = 0.f; }

  // prefetch tile 0
  bf16x8v ac[4], an[4];
  {
    const unsigned short* rp = zb + (size_t)(cStart + lr) * DD + lg * 8;
    ac[0] = *reinterpret_cast<const bf16x8v*>(rp);
    ac[1] = *reinterpret_cast<const bf16x8v*>(rp + 32);
    ac[2] = *reinterpret_cast<const bf16x8v*>(rp + 64);
    ac[3] = *reinterpret_cast<const bf16x8v*>(rp + 96);
  }

#pragma unroll 2
  for (int tt = 0; tt < CPC / 16; ++tt) {
    const int c0 = cStart + tt * 16;
    if (tt + 1 < CPC / 16) {       // prefetch next tile while computing this one
      const unsigned short* rp = zb + (size_t)(c0 + 16 + lr) * DD + lg * 8;
      an[0] = *reinterpret_cast<const bf16x8v*>(rp);
      an[1] = *reinterpret_cast<const bf16x8v*>(rp + 32);
      an[2] = *reinterpret_cast<const bf16x8v*>(rp + 64);
      an[3] = *reinterpret_cast<const bf16x8v*>(rp + 96);
    }

    f32x4 acc[4];
#pragma unroll
    for (int t = 0; t < 4; ++t) {
      f32x4 a = (f32x4){0.f, 0.f, 0.f, 0.f};
      a = __builtin_amdgcn_mfma_f32_16x16x32_bf16(ac[0], bfr[t][0], a, 0, 0, 0);
      a = __builtin_amdgcn_mfma_f32_16x16x32_bf16(ac[1], bfr[t][1], a, 0, 0, 0);
      a = __builtin_amdgcn_mfma_f32_16x16x32_bf16(ac[2], bfr[t][2], a, 0, 0, 0);
      a = __builtin_amdgcn_mfma_f32_16x16x32_bf16(ac[3], bfr[t][3], a, 0, 0, 0);
      acc[t] = a;
    }

    const int dcl = c0 - rowstart;
    if ((unsigned)dcl < (unsigned)AW) tile_lse<true >(acc, dcl, lr, lg, m, s);
    else                              tile_lse<false>(acc, 0,   lr, lg, m, s);

#pragma unroll
    for (int k = 0; k < 4; ++k) ac[k] = an[k];
  }

  // merge the 4 lane-groups (xor 16, 32)
#pragma unroll
  for (int off = 16; off <= 32; off <<= 1) {
#pragma unroll
    for (int t = 0; t < 4; ++t) {
      float mo = __shfl_xor(m[t], off);
      float so = __shfl_xor(s[t], off);
      float mn = fmaxf(m[t], mo);
      s[t] = s[t] * ex2(m[t] - mn) + so * ex2(mo - mn);
      m[t] = mn;
    }
  }
  if (lg == 0) {
#pragma unroll
    for (int t = 0; t < 4; ++t)
      partials[(size_t)(rowstart + t * 16 + lr) * NC + cb] = make_float2(m[t], s[t]);
  }
}

// ---------------- kernel 3: per-class merge + exact correction + loss ----------------
__global__ __launch_bounds__(256) void k_corr(const unsigned short* __restrict__ zb,
                                              const int* __restrict__ labels,
                                              const float2* __restrict__ partials,
                                              float* __restrict__ clsum) {
  const int c = blockIdx.x;
  const int tid = threadIdx.x, lane = tid & 63, w = tid >> 6;
  __shared__ int rows[CAPR];
  __shared__ float rowm[CAPR], rowss[CAPR];
  __shared__ int nsh;
  __shared__ float clpart[4];

  // wave-synchronous deterministic compaction (wave 0 only)
  if (w == 0) {
    int base = 0;
    for (int rd = 0; rd < NN / 256; ++rd) {
      int4 v = *reinterpret_cast<const int4*>(labels + rd * 256 + lane * 4);
      int labq[4] = {v.x, v.y, v.z, v.w};
#pragma unroll
      for (int q = 0; q < 4; ++q) {
        bool mt = (labq[q] == c);
        unsigned long long mask = __ballot(mt);
        if (mt) {
          int p = base + __popcll(mask & ((1ull << lane) - 1ull));
          if (p < CAPR) rows[p] = rd * 256 + lane * 4 + q;
        }
        base += __popcll(mask);
      }
    }
    if (lane == 0) nsh = base < CAPR ? base : CAPR;
  }
  __syncthreads();
  const int n = nsh;
  if (n < 2) { if (tid == 0) clsum[c] = 0.f; return; }

  // merge the NC chunk-partials for this class's rows (row-major: streaming reads)
  for (int r = tid; r < n; r += 256) {
    const float2* p = partials + (size_t)rows[r] * NC;
    float m = M_INIT, s = 0.f;
    for (int ch = 0; ch < NC; ++ch) {
      float2 q = p[ch];
      float mn = fmaxf(m, q.x);
      s = s * ex2(m - mn) + q.y * ex2(q.x - mn);
      m = mn;
    }
    rowm[r] = m; rowss[r] = s;
  }
  __syncthreads();

  const int lr = lane & 15, lg = lane >> 4;
  const int NB = (n + 15) >> 4;
  float wloss = 0.f;
  for (int ab = w; ab < NB; ab += 4) {
    int a = ab * 16 + lr;
    bool aok = a < n;
    int ga = rows[aok ? a : 0];
    bf16x8v bf[4];
#pragma unroll
    for (int ks = 0; ks < 4; ++ks)
      bf[ks] = *reinterpret_cast<const bf16x8v*>(zb + (size_t)ga * DD + ks * 32 + lg * 8);
    float ma = aok ? rowm[a] : 0.f;
    float sumv = 0.f, sume = 0.f;
    for (int bb = 0; bb < NB; ++bb) {
      int bi = bb * 16 + lr;
      int gb = rows[bi < n ? bi : 0];
      bf16x8v af[4];
#pragma unroll
      for (int ks = 0; ks < 4; ++ks)
        af[ks] = *reinterpret_cast<const bf16x8v*>(zb + (size_t)gb * DD + ks * 32 + lg * 8);
      f32x4 acc = (f32x4){0.f, 0.f, 0.f, 0.f};
      acc = __builtin_amdgcn_mfma_f32_16x16x32_bf16(af[0], bf[0], acc, 0, 0, 0);
      acc = __builtin_amdgcn_mfma_f32_16x16x32_bf16(af[1], bf[1], acc, 0, 0, 0);
      acc = __builtin_amdgcn_mfma_f32_16x16x32_bf16(af[2], bf[2], acc, 0, 0, 0);
      acc = __builtin_amdgcn_mfma_f32_16x16x32_bf16(af[3], bf[3], acc, 0, 0, 0);
#pragma unroll
      for (int r = 0; r < 4; ++r) {
        int b = bb * 16 + lg * 4 + r;
        bool ok = (b < n) && (b != a);
        float v = acc[r];
        sumv += ok ? v : 0.f;
        float e = ex2(v - ma);
        sume += ok ? e : 0.f;
      }
    }
#pragma unroll
    for (int off = 16; off <= 32; off <<= 1) {
      sumv += __shfl_xor(sumv, off);
      sume += __shfl_xor(sume, off);
    }
    if (lg == 0 && aok) {
      float sp = rowss[a] - 0.5f * sume;           // apply 0.5 weight to matches
      wloss += LN2 * (ma + log2f(sp)) - LN2 * sumv / (float)(n - 1);
    }
  }
#pragma unroll
  for (int off = 32; off >= 1; off >>= 1) wloss += __shfl_xor(wloss, off);
  if (lane == 0) clpart[w] = wloss;
  __syncthreads();
  if (tid == 0) clsum[c] = (clpart[0] + clpart[1]) + (clpart[2] + clpart[3]);
}

// ---------------- kernel 4: final sum over classes ----------------
__global__ __launch_bounds__(128) void k_final(const float* __restrict__ clsum,
                                               float* __restrict__ out) {
  const int tid = threadIdx.x;
  float v = (tid < NCLS) ? clsum[tid] : 0.f;
#pragma unroll
  for (int off = 32; off >= 1; off >>= 1) v += __shfl_xor(v, off);
  __shared__ float t2[2];
  if ((tid & 63) == 0) t2[tid >> 6] = v;
  __syncthreads();
  if (tid == 0) out[0] = (t2[0] + t2[1]) * (1.0f / (float)NN);
}

extern "C" void kernel_launch(void* const* d_in, const int* in_sizes, int n_in,
                              void* d_out, int out_size, void* d_ws, size_t ws_size,
                              hipStream_t stream) {
  const float* z      = (const float*)d_in[0];
  const int*   labels = (const int*)d_in[1];

  char* ws = (char*)d_ws;
  unsigned short* zb = (unsigned short*)ws;                                 // 2 MB
  float2* partials   = (float2*)(ws + (size_t)NN * DD * 2);                 // NN*NC*8 = 2 MB
  float*  clsum      = (float*)(ws + (size_t)NN * DD * 2 + (size_t)NN * NC * 8);

  hipLaunchKernelGGL(k_convert, dim3(NN * DD / 4 / 256), dim3(256), 0, stream, z, zb);
  hipLaunchKernelGGL(k_main,    dim3(NN / (4 * AW), NC), dim3(256), 0, stream, zb, partials);
  hipLaunchKernelGGL(k_corr,    dim3(NCLS), dim3(256), 0, stream, zb, labels, partials, clsum);
  hipLaunchKernelGGL(k_final,   dim3(1), dim3(128), 0, stream, clsum, (float*)d_out);
}